// Round 12
// baseline (206.749 us; speedup 1.0000x reference)
//
#include <hip/hip_runtime.h>
#include <hip/hip_bf16.h>

typedef __attribute__((ext_vector_type(8))) short bf16x8;
typedef __attribute__((ext_vector_type(4))) float f32x4;
typedef __attribute__((ext_vector_type(4))) unsigned u32x4;

#define NEG 0.2f
#define CST 104   // bf16 elems per LDS row (208 B stride)

__device__ __forceinline__ float lrelu(float x) { return x >= 0.0f ? x : NEG * x; }

__device__ __forceinline__ unsigned short f2bf(float x) {
    unsigned u = __builtin_bit_cast(unsigned, x);
    u += 0x7FFFu + ((u >> 16) & 1u);
    return (unsigned short)(u >> 16);
}
// packed pair via v_cvt_pk_bf16_f32 (RNE): low 16 = a, high 16 = b
__device__ __forceinline__ unsigned pk2(float a, float b) {
    __hip_bfloat162 h = __float22bfloat162_rn(float2{a, b});
    unsigned r;
    __builtin_memcpy(&r, &h, sizeof(r));
    return r;
}

__device__ __forceinline__ void red16(f32x4& v) {   // sum over 16-lane lr groups
#pragma unroll
    for (int d = 1; d < 16; d <<= 1) {
        v.x += __shfl_xor(v.x, d);
        v.y += __shfl_xor(v.y, d);
        v.z += __shfl_xor(v.z, d);
        v.w += __shfl_xor(v.w, d);
    }
}

// One block per t. 512 threads = 8 waves, one 16-row tile per wave (wave 7
// duplicates tile 6, writes suppressed). LDS 51072 B.
// LDS: P  [112][104] bf16 @0     : X (until xf hoisted) -> W_h per head
//      HT [112][104] bf16 @23296 : H^T[o][j] per head  (zero-initialized)
//      sas[112] sad[112] @46592 (f32); sas[100..111] = -1e30 (pad kill)
//      satS[4][112] @47488, satD[4][112] @49280 (pads zeroed)
//      sOut f32 [112][104] overlay @0 at the end.
// 3 barriers/head: (b) W ready, (c) HT+logits ready, (d) PV done -> P writable.
// W_{h+1} register-prefetched after (c); LDS-written after (d) -> latency
// hidden under PVprep+PV; write provably fenced. No uninitialized LDS reads.
extern "C" __global__ void __launch_bounds__(512, 4)
gat11(const float* __restrict__ A, const float* __restrict__ W,
      const float* __restrict__ att_src, const float* __restrict__ att_dst,
      const float* __restrict__ bias, float* __restrict__ out)
{
    extern __shared__ char smem[];
    unsigned short* P  = (unsigned short*)smem;
    unsigned short* HT = (unsigned short*)(smem + 23296);
    float* sas  = (float*)(smem + 46592);
    float* sad  = sas + 112;
    float* satS = (float*)(smem + 47488);   // [4][112]
    float* satD = (float*)(smem + 49280);   // [4][112]
    float* sOut = (float*)smem;

    const int t    = blockIdx.x;
    const int tid  = threadIdx.x;      // 0..511
    const int w    = tid >> 6;         // 0..7
    const int l    = tid & 63;
    const int lr   = l & 15;
    const int lk   = l >> 4;
    const bool HASW = (w < 7);
    const int row  = HASW ? w : 6;
    const int j0   = row * 16 + 4 * lk;        // 0..108
    const bool JW  = HASW && (j0 < 104);
    const float* __restrict__ At = A + (size_t)t * 10000u;

    // ---- per-thread W-chunk map (static, reused every head) ----
    int offk[6], dstk[6];
    bool qok[6], okk[6];
#pragma unroll
    for (int k = 0; k < 6; ++k) {
        const int q = tid + k * 512;
        const int o = q / 26, f0 = (q - o * 26) * 4;
        qok[k] = (q < 2912);
        okk[k] = qok[k] && (o < 100) && (f0 < 100);
        offk[k] = o * 100 + f0;
        dstk[k] = o * CST + f0;
    }
    const f32x4 z4 = {0, 0, 0, 0};
    // ---- prefetch W_0 (latency hides under init + staging below) ----
    float4 wv[6];
#pragma unroll
    for (int k = 0; k < 6; ++k)
        wv[k] = okk[k] ? *(const float4*)(W + offk[k]) : (float4){0, 0, 0, 0};

    // ---- zero P AND HT; init sas/sad; stage att (pads zeroed) ----
    for (int i = tid; i < 2912; i += 512) ((f32x4*)smem)[i] = z4;
    if (tid < 224) {
        float v = (tid >= 100 && tid < 112) ? -1e30f : 0.0f;
        ((float*)(smem + 46592))[tid] = v;
    }
    for (int i = tid; i < 896; i += 512) {
        const int which = i / 448;
        const int r2 = i - which * 448;
        const int hh = r2 / 112, oo = r2 - hh * 112;
        const float v = (oo < 100)
            ? (which ? att_dst[hh * 100 + oo] : att_src[hh * 100 + oo]) : 0.0f;
        (which ? satD : satS)[r2] = v;
    }
    __syncthreads();

    // ---- stage A_t^T -> P[n][f] bf16 (pk2 pairs along f) ----
#pragma unroll
    for (int k = 0; k < 3; ++k) {
        const int q = tid + k * 512;
        if (q < 1250) {
            const int fp = q / 25, n0 = (q - fp * 25) * 4, f = fp * 2;
            float4 va = *(const float4*)(At + f * 100 + n0);
            float4 vb = *(const float4*)(At + (f + 1) * 100 + n0);
            *(unsigned*)(P + (n0 + 0) * CST + f) = pk2(va.x, vb.x);
            *(unsigned*)(P + (n0 + 1) * CST + f) = pk2(va.y, vb.y);
            *(unsigned*)(P + (n0 + 2) * CST + f) = pk2(va.z, vb.z);
            *(unsigned*)(P + (n0 + 3) * CST + f) = pk2(va.w, vb.w);
        }
    }
    __syncthreads();

    // ---- hoist X fragments ----
    const bf16x8 zf = {0, 0, 0, 0, 0, 0, 0, 0};
    bf16x8 xf[4];
#pragma unroll
    for (int ks = 0; ks < 4; ++ks) {
        const bool kill = (ks == 3) && (lk != 0);
        const int koff = kill ? 96 : ks * 32 + lk * 8;
        bf16x8 v = *(const bf16x8*)(P + (row * 16 + lr) * CST + koff);
        xf[ks] = kill ? zf : v;
    }
    __syncthreads();   // (d0) hoist done -> P writable

    f32x4 acc[7];
#pragma unroll
    for (int c = 0; c < 7; ++c) acc[c] = z4;

    for (int h = 0; h < 4; ++h) {
        // ---- Wfill write: wv (= W_h) -> P bf16 (after (d): P provably idle) ----
#pragma unroll
        for (int k = 0; k < 6; ++k) {
            if (qok[k]) {
                uint2 pp;
                pp.x = pk2(wv[k].x, wv[k].y);
                pp.y = pk2(wv[k].z, wv[k].w);
                *(uint2*)(P + dstk[k]) = pp;
            }
        }
        __syncthreads();   // (b) W ready

        // ---- GEMM-1 (+ in-register logit partials), two N-halves ----
        f32x4 pS = z4, pD = z4;
#pragma unroll
        for (int half = 0; half < 2; ++half) {
            const int ntn = half ? 3 : 4;
            f32x4 c[4];
#pragma unroll
            for (int cc = 0; cc < 4; ++cc) c[cc] = z4;
#pragma unroll
            for (int ks = 0; ks < 4; ++ks) {
                const int koff = ks * 32 + lk * 8;   // A-side zero kills k-pad
                bf16x8 b[4];
#pragma unroll
                for (int bb = 0; bb < 4; ++bb)
                    if (bb < ntn)
                        b[bb] = *(const bf16x8*)(P + ((half * 4 + bb) * 16 + lr) * CST + koff);
#pragma unroll
                for (int bb = 0; bb < 4; ++bb)
                    if (bb < ntn)
                        c[bb] = __builtin_amdgcn_mfma_f32_16x16x32_bf16(xf[ks], b[bb], c[bb], 0, 0, 0);
            }
#pragma unroll
            for (int bb = 0; bb < 4; ++bb)
                if (bb < ntn) {
                    const int o = (half * 4 + bb) * 16 + lr;
                    const bool vv = (o < 100);
                    const float aS = vv ? satS[h * 112 + o] : 0.0f;
                    const float aD = vv ? satD[h * 112 + o] : 0.0f;
                    pS += c[bb] * aS;
                    pD += c[bb] * aD;
                    if (JW) {
                        uint2 pp;
                        pp.x = pk2(c[bb].x, c[bb].y);
                        pp.y = pk2(c[bb].z, c[bb].w);
                        *(uint2*)(HT + o * CST + j0) = pp;
                    }
                }
        }
        red16(pS); red16(pD);
        if (lr == 0) {
            if (HASW && j0 < 100) *(f32x4*)(sas + j0) = pS;
            if (JW)               *(f32x4*)(sad + j0) = pD;
        }
        __syncthreads();   // (c) HT + sas/sad ready

        // ---- prefetch W_{h+1} (latency hides under PVprep + PV) ----
        if (h < 3) {
            const float* Wn = W + (h + 1) * 10000;
#pragma unroll
            for (int k = 0; k < 6; ++k)
                wv[k] = okk[k] ? *(const float4*)(Wn + offk[k]) : (float4){0, 0, 0, 0};
        }

        // ---- PVprep: f32 E + row-sum, normalize, pack bf16 (r10 numerics) ----
        const float adi = sad[row * 16 + lr];
        float ev[32];
        float sE = 0.0f;
#pragma unroll
        for (int ks = 0; ks < 4; ++ks) {
            const bool dead = (ks == 3) && (lk != 0);
            const int jb = dead ? 64 : ks * 32 + lk * 8;
            const f32x4 s0 = *(const f32x4*)(sas + jb);
            const f32x4 s1 = *(const f32x4*)(sas + jb + 4);
            ev[ks * 8 + 0] = dead ? 0.0f : __expf(lrelu(adi + s0.x));
            ev[ks * 8 + 1] = dead ? 0.0f : __expf(lrelu(adi + s0.y));
            ev[ks * 8 + 2] = dead ? 0.0f : __expf(lrelu(adi + s0.z));
            ev[ks * 8 + 3] = dead ? 0.0f : __expf(lrelu(adi + s0.w));
            ev[ks * 8 + 4] = dead ? 0.0f : __expf(lrelu(adi + s1.x));
            ev[ks * 8 + 5] = dead ? 0.0f : __expf(lrelu(adi + s1.y));
            ev[ks * 8 + 6] = dead ? 0.0f : __expf(lrelu(adi + s1.z));
            ev[ks * 8 + 7] = dead ? 0.0f : __expf(lrelu(adi + s1.w));
#pragma unroll
            for (int jj = 0; jj < 8; ++jj) sE += ev[ks * 8 + jj];
        }
        sE += __shfl_xor(sE, 16);
        sE += __shfl_xor(sE, 32);
        const float invE = sE > 0.0f ? __builtin_amdgcn_rcpf(sE) : 0.0f;
        bf16x8 af[4];
#pragma unroll
        for (int ks = 0; ks < 4; ++ks) {
            u32x4 uv;
            uv.x = pk2(ev[ks * 8 + 0] * invE, ev[ks * 8 + 1] * invE);
            uv.y = pk2(ev[ks * 8 + 2] * invE, ev[ks * 8 + 3] * invE);
            uv.z = pk2(ev[ks * 8 + 4] * invE, ev[ks * 8 + 5] * invE);
            uv.w = pk2(ev[ks * 8 + 6] * invE, ev[ks * 8 + 7] * invE);
            af[ks] = __builtin_bit_cast(bf16x8, uv);
        }

        // ---- PV: acc += alpha * H (direct C accumulation) ----
#pragma unroll
        for (int half = 0; half < 2; ++half) {
            const int ntn = half ? 3 : 4;
#pragma unroll
            for (int ks = 0; ks < 4; ++ks) {
                const int koff = ks * 32 + lk * 8;
                bf16x8 b[4];
#pragma unroll
                for (int bb = 0; bb < 4; ++bb)
                    if (bb < ntn)
                        b[bb] = *(const bf16x8*)(HT + ((half * 4 + bb) * 16 + lr) * CST + koff);
#pragma unroll
                for (int bb = 0; bb < 4; ++bb)
                    if (bb < ntn)
                        acc[half * 4 + bb] = __builtin_amdgcn_mfma_f32_16x16x32_bf16(
                            af[ks], b[bb], acc[half * 4 + bb], 0, 0, 0);
            }
        }
        __syncthreads();   // (d) PV done -> P (and HT) writable next head
    }

    // ---- epilogue: sOut[o][i] = lrelu(acc*0.25 + bias[o]) + (i==o) ----
    if (JW) {
        const int i0 = j0;
#pragma unroll
        for (int tn = 0; tn < 7; ++tn) {
            const int o = tn * 16 + lr;
            const float b = (o < 100) ? bias[o] : 0.0f;
            f32x4 v;
            v.x = lrelu(acc[tn].x * 0.25f + b) + ((i0 + 0) == o ? 1.0f : 0.0f);
            v.y = lrelu(acc[tn].y * 0.25f + b) + ((i0 + 1) == o ? 1.0f : 0.0f);
            v.z = lrelu(acc[tn].z * 0.25f + b) + ((i0 + 2) == o ? 1.0f : 0.0f);
            v.w = lrelu(acc[tn].w * 0.25f + b) + ((i0 + 3) == o ? 1.0f : 0.0f);
            *(f32x4*)(sOut + o * 104 + i0) = v;
        }
    }
    __syncthreads();

    // ---- coalesced store out[t][o][i] ----
    float* __restrict__ outT = out + (size_t)t * 10000u;
    for (int q = tid; q < 2500; q += 512) {
        int o = q / 25, i0 = (q - o * 25) * 4;
        *(float4*)(outT + o * 100 + i0) = *(const float4*)(sOut + o * 104 + i0);
    }
}

extern "C" void kernel_launch(void* const* d_in, const int* in_sizes, int n_in,
                              void* d_out, int out_size, void* d_ws, size_t ws_size,
                              hipStream_t stream) {
    const float* A      = (const float*)d_in[0];
    const float* W      = (const float*)d_in[1];
    const float* attsrc = (const float*)d_in[2];
    const float* attdst = (const float*)d_in[3];
    const float* bias   = (const float*)d_in[4];
    float* outp = (float*)d_out;

    const int T = in_sizes[0] / 10000;   // 1024
    const int smem_bytes = 51072;
    gat11<<<T, 512, smem_bytes, stream>>>(A, W, attsrc, attdst, bias, outp);
}

// Round 13
// 122.035 us; speedup vs baseline: 1.6942x; 1.6942x over previous
//
#include <hip/hip_runtime.h>
#include <hip/hip_bf16.h>

typedef __attribute__((ext_vector_type(8))) short bf16x8;
typedef __attribute__((ext_vector_type(4))) float f32x4;
typedef __attribute__((ext_vector_type(4))) unsigned u32x4;

#define NEG 0.2f
#define CST 104   // bf16 elems per LDS row (208 B stride)

__device__ __forceinline__ float lrelu(float x) { return x >= 0.0f ? x : NEG * x; }

// packed pair via v_cvt_pk_bf16_f32 (RNE): low 16 = a, high 16 = b
__device__ __forceinline__ unsigned pk2(float a, float b) {
    __hip_bfloat162 h = __float22bfloat162_rn(float2{a, b});
    unsigned r;
    __builtin_memcpy(&r, &h, sizeof(r));
    return r;
}

__device__ __forceinline__ void red16(f32x4& v) {   // sum over 16-lane lr groups
#pragma unroll
    for (int d = 1; d < 16; d <<= 1) {
        v.x += __shfl_xor(v.x, d);
        v.y += __shfl_xor(v.y, d);
        v.z += __shfl_xor(v.z, d);
        v.w += __shfl_xor(v.w, d);
    }
}

// One block per t. 512 threads = 8 waves, one 16-row tile per wave (wave 7
// duplicates tile 6, writes suppressed). LDS 74368 B -> 2 blocks/CU.
// LDS: Wb0 [112][104] bf16 @0     : W_{even heads}
//      Wb1 [112][104] bf16 @23296 : W_{odd heads}
//      HT  [112][104] bf16 @46592 : X staging (once) -> H^T[o][j] per head
//      sas[112] sad[112] @69888 (f32); sas[100..111] = -1e30 (pad kill)
//      satS[4][112] @70784, satD[4][112] @72576 (pads zeroed)
//      sOut f32 [112][104] overlay @0 (over Wb0+Wb1) at the end.
// 2 barriers/head. W double-buffered in LDS: Wfill(h+1) -> Wb[(h+1)&1] placed
// BEFORE GEMM-1(h) (reads Wb[h&1]) so W-load latency is hidden by other
// waves' MFMAs (stagger) with ZERO persistent registers (r12's spill lesson).
extern "C" __global__ void __launch_bounds__(512, 4)
gat12(const float* __restrict__ A, const float* __restrict__ W,
      const float* __restrict__ att_src, const float* __restrict__ att_dst,
      const float* __restrict__ bias, float* __restrict__ out)
{
    extern __shared__ char smem[];
    unsigned short* Wb0 = (unsigned short*)smem;
    unsigned short* Wb1 = (unsigned short*)(smem + 23296);
    unsigned short* HT  = (unsigned short*)(smem + 46592);
    float* sas  = (float*)(smem + 69888);
    float* sad  = sas + 112;
    float* satS = (float*)(smem + 70784);   // [4][112]
    float* satD = (float*)(smem + 72576);   // [4][112]
    float* sOut = (float*)smem;

    const int t    = blockIdx.x;
    const int tid  = threadIdx.x;      // 0..511
    const int w    = tid >> 6;         // 0..7
    const int l    = tid & 63;
    const int lr   = l & 15;
    const int lk   = l >> 4;
    const bool HASW = (w < 7);
    const int row  = HASW ? w : 6;     // wave 7 duplicates tile 6
    const int j0   = row * 16 + 4 * lk;        // 0..108
    const bool JW  = HASW && (j0 < 104);
    const float* __restrict__ At = A + (size_t)t * 10000u;
    const f32x4 z4 = {0, 0, 0, 0};

    // ---- zero Wb0+Wb1+HT (69888 B); init stats; stage att (pads zeroed) ----
    for (int i = tid; i < 4368; i += 512) ((f32x4*)smem)[i] = z4;
    if (tid < 224) {
        float v = (tid >= 100 && tid < 112) ? -1e30f : 0.0f;
        ((float*)(smem + 69888))[tid] = v;   // sas[112] + sad[112]
    }
    for (int i = tid; i < 896; i += 512) {
        const int which = i / 448;
        const int r2 = i - which * 448;
        const int hh = r2 / 112, oo = r2 - hh * 112;
        const float v = (oo < 100)
            ? (which ? att_dst[hh * 100 + oo] : att_src[hh * 100 + oo]) : 0.0f;
        (which ? satD : satS)[r2] = v;
    }
    __syncthreads();

    // ---- stage A_t^T -> HT region [n][f] bf16 (pk2 pairs along f) ----
#pragma unroll
    for (int k = 0; k < 3; ++k) {
        const int q = tid + k * 512;
        if (q < 1250) {
            const int fp = q / 25, n0 = (q - fp * 25) * 4, f = fp * 2;
            float4 va = *(const float4*)(At + f * 100 + n0);
            float4 vb = *(const float4*)(At + (f + 1) * 100 + n0);
            *(unsigned*)(HT + (n0 + 0) * CST + f) = pk2(va.x, vb.x);
            *(unsigned*)(HT + (n0 + 1) * CST + f) = pk2(va.y, vb.y);
            *(unsigned*)(HT + (n0 + 2) * CST + f) = pk2(va.z, vb.z);
            *(unsigned*)(HT + (n0 + 3) * CST + f) = pk2(va.w, vb.w);
        }
    }
    __syncthreads();

    // ---- hoist X fragments from HT region ----
    const bf16x8 zf = {0, 0, 0, 0, 0, 0, 0, 0};
    bf16x8 xf[4];
#pragma unroll
    for (int ks = 0; ks < 4; ++ks) {
        const bool kill = (ks == 3) && (lk != 0);
        const int koff = kill ? 96 : ks * 32 + lk * 8;
        bf16x8 v = *(const bf16x8*)(HT + (row * 16 + lr) * CST + koff);
        xf[ks] = kill ? zf : v;
    }
    __syncthreads();   // HT region free for GEMM-1 output

    // ---- Wfill head 0 -> Wb0 (cold, once per block) ----
    for (int q = tid; q < 2912; q += 512) {
        const int o = q / 26, f0 = (q - o * 26) * 4;
        uint2 pp = {0u, 0u};
        if (o < 100 && f0 < 100) {
            float4 wv = *(const float4*)(W + o * 100 + f0);
            pp.x = pk2(wv.x, wv.y);
            pp.y = pk2(wv.z, wv.w);
        }
        *(uint2*)(Wb0 + o * CST + f0) = pp;
    }
    __syncthreads();   // (b0) Wb0 ready

    f32x4 acc[7];
#pragma unroll
    for (int c = 0; c < 7; ++c) acc[c] = z4;

    for (int h = 0; h < 4; ++h) {
        const unsigned short* Wc = (h & 1) ? Wb1 : Wb0;

        // ---- Wfill(h+1) -> other buffer; latency hidden by other waves' MFMAs ----
        if (h < 3) {
            unsigned short* Wn = (h & 1) ? Wb0 : Wb1;
            const float* Wg = W + (h + 1) * 10000;
            for (int q = tid; q < 2912; q += 512) {
                const int o = q / 26, f0 = (q - o * 26) * 4;
                uint2 pp = {0u, 0u};
                if (o < 100 && f0 < 100) {
                    float4 wv = *(const float4*)(Wg + o * 100 + f0);
                    pp.x = pk2(wv.x, wv.y);
                    pp.y = pk2(wv.z, wv.w);
                }
                *(uint2*)(Wn + o * CST + f0) = pp;
            }
        }

        // ---- GEMM-1 (+ in-register logit partials), two N-halves ----
        f32x4 pS = z4, pD = z4;
#pragma unroll
        for (int half = 0; half < 2; ++half) {
            const int ntn = half ? 3 : 4;
            f32x4 c[4];
#pragma unroll
            for (int cc = 0; cc < 4; ++cc) c[cc] = z4;
#pragma unroll
            for (int ks = 0; ks < 4; ++ks) {
                const int koff = ks * 32 + lk * 8;   // A-side zero kills k-pad
                bf16x8 b[4];
#pragma unroll
                for (int bb = 0; bb < 4; ++bb)
                    if (bb < ntn)
                        b[bb] = *(const bf16x8*)(Wc + ((half * 4 + bb) * 16 + lr) * CST + koff);
#pragma unroll
                for (int bb = 0; bb < 4; ++bb)
                    if (bb < ntn)
                        c[bb] = __builtin_amdgcn_mfma_f32_16x16x32_bf16(xf[ks], b[bb], c[bb], 0, 0, 0);
            }
#pragma unroll
            for (int bb = 0; bb < 4; ++bb)
                if (bb < ntn) {
                    const int o = (half * 4 + bb) * 16 + lr;
                    const bool vv = (o < 100);
                    const float aS = vv ? satS[h * 112 + o] : 0.0f;
                    const float aD = vv ? satD[h * 112 + o] : 0.0f;
                    pS += c[bb] * aS;
                    pD += c[bb] * aD;
                    if (JW) {
                        uint2 pp;
                        pp.x = pk2(c[bb].x, c[bb].y);
                        pp.y = pk2(c[bb].z, c[bb].w);
                        *(uint2*)(HT + o * CST + j0) = pp;
                    }
                }
        }
        red16(pS); red16(pD);
        if (lr == 0) {
            if (HASW && j0 < 100) *(f32x4*)(sas + j0) = pS;
            if (JW)               *(f32x4*)(sad + j0) = pD;
        }
        __syncthreads();   // (c) HT + sas/sad ready

        // ---- PVprep: f32 E + row-sum, normalize, pack bf16 (r10 numerics) ----
        const float adi = sad[row * 16 + lr];
        float ev[32];
        float sE = 0.0f;
#pragma unroll
        for (int ks = 0; ks < 4; ++ks) {
            const bool dead = (ks == 3) && (lk != 0);
            const int jb = dead ? 64 : ks * 32 + lk * 8;
            const f32x4 s0 = *(const f32x4*)(sas + jb);
            const f32x4 s1 = *(const f32x4*)(sas + jb + 4);
            ev[ks * 8 + 0] = dead ? 0.0f : __expf(lrelu(adi + s0.x));
            ev[ks * 8 + 1] = dead ? 0.0f : __expf(lrelu(adi + s0.y));
            ev[ks * 8 + 2] = dead ? 0.0f : __expf(lrelu(adi + s0.z));
            ev[ks * 8 + 3] = dead ? 0.0f : __expf(lrelu(adi + s0.w));
            ev[ks * 8 + 4] = dead ? 0.0f : __expf(lrelu(adi + s1.x));
            ev[ks * 8 + 5] = dead ? 0.0f : __expf(lrelu(adi + s1.y));
            ev[ks * 8 + 6] = dead ? 0.0f : __expf(lrelu(adi + s1.z));
            ev[ks * 8 + 7] = dead ? 0.0f : __expf(lrelu(adi + s1.w));
#pragma unroll
            for (int jj = 0; jj < 8; ++jj) sE += ev[ks * 8 + jj];
        }
        sE += __shfl_xor(sE, 16);
        sE += __shfl_xor(sE, 32);
        const float invE = sE > 0.0f ? __builtin_amdgcn_rcpf(sE) : 0.0f;
        bf16x8 af[4];
#pragma unroll
        for (int ks = 0; ks < 4; ++ks) {
            u32x4 uv;
            uv.x = pk2(ev[ks * 8 + 0] * invE, ev[ks * 8 + 1] * invE);
            uv.y = pk2(ev[ks * 8 + 2] * invE, ev[ks * 8 + 3] * invE);
            uv.z = pk2(ev[ks * 8 + 4] * invE, ev[ks * 8 + 5] * invE);
            uv.w = pk2(ev[ks * 8 + 6] * invE, ev[ks * 8 + 7] * invE);
            af[ks] = __builtin_bit_cast(bf16x8, uv);
        }

        // ---- PV: acc += alpha * H (direct C accumulation) ----
#pragma unroll
        for (int half = 0; half < 2; ++half) {
            const int ntn = half ? 3 : 4;
#pragma unroll
            for (int ks = 0; ks < 4; ++ks) {
                const int koff = ks * 32 + lk * 8;
                bf16x8 b[4];
#pragma unroll
                for (int bb = 0; bb < 4; ++bb)
                    if (bb < ntn)
                        b[bb] = *(const bf16x8*)(HT + ((half * 4 + bb) * 16 + lr) * CST + koff);
#pragma unroll
                for (int bb = 0; bb < 4; ++bb)
                    if (bb < ntn)
                        acc[half * 4 + bb] = __builtin_amdgcn_mfma_f32_16x16x32_bf16(
                            af[ks], b[bb], acc[half * 4 + bb], 0, 0, 0);
            }
        }
        __syncthreads();   // (d)=(b_{h+1}): PV done; HT writable; Wfill flushed
    }

    // ---- epilogue: sOut[o][i] = lrelu(acc*0.25 + bias[o]) + (i==o) ----
    if (JW) {
        const int i0 = j0;
#pragma unroll
        for (int tn = 0; tn < 7; ++tn) {
            const int o = tn * 16 + lr;
            const float b = (o < 100) ? bias[o] : 0.0f;
            f32x4 v;
            v.x = lrelu(acc[tn].x * 0.25f + b) + ((i0 + 0) == o ? 1.0f : 0.0f);
            v.y = lrelu(acc[tn].y * 0.25f + b) + ((i0 + 1) == o ? 1.0f : 0.0f);
            v.z = lrelu(acc[tn].z * 0.25f + b) + ((i0 + 2) == o ? 1.0f : 0.0f);
            v.w = lrelu(acc[tn].w * 0.25f + b) + ((i0 + 3) == o ? 1.0f : 0.0f);
            *(f32x4*)(sOut + o * 104 + i0) = v;
        }
    }
    __syncthreads();

    // ---- coalesced store out[t][o][i] ----
    float* __restrict__ outT = out + (size_t)t * 10000u;
    for (int q = tid; q < 2500; q += 512) {
        int o = q / 25, i0 = (q - o * 25) * 4;
        *(float4*)(outT + o * 100 + i0) = *(const float4*)(sOut + o * 104 + i0);
    }
}

extern "C" void kernel_launch(void* const* d_in, const int* in_sizes, int n_in,
                              void* d_out, int out_size, void* d_ws, size_t ws_size,
                              hipStream_t stream) {
    const float* A      = (const float*)d_in[0];
    const float* W      = (const float*)d_in[1];
    const float* attsrc = (const float*)d_in[2];
    const float* attdst = (const float*)d_in[3];
    const float* bias   = (const float*)d_in[4];
    float* outp = (float*)d_out;

    const int T = in_sizes[0] / 10000;   // 1024
    const int smem_bytes = 74368;
    hipFuncSetAttribute((const void*)gat12,
                        hipFuncAttributeMaxDynamicSharedMemorySize, smem_bytes);
    gat12<<<T, 512, smem_bytes, stream>>>(A, W, attsrc, attdst, bias, outp);
}

// Round 14
// 109.592 us; speedup vs baseline: 1.8865x; 1.1135x over previous
//
#include <hip/hip_runtime.h>
#include <hip/hip_bf16.h>

typedef __attribute__((ext_vector_type(8))) short bf16x8;
typedef __attribute__((ext_vector_type(4))) float f32x4;
typedef __attribute__((ext_vector_type(4))) unsigned u32x4;

#define NEG 0.2f
#define CST 104     // bf16 elems per LDS row (208 B stride)
#define HSTRIDE 11648   // 112*104 bf16 elems per head in d_ws

__device__ __forceinline__ float lrelu(float x) { return x >= 0.0f ? x : NEG * x; }

__device__ __forceinline__ unsigned short f2bf(float x) {
    unsigned u = __builtin_bit_cast(unsigned, x);
    u += 0x7FFFu + ((u >> 16) & 1u);   // RNE
    return (unsigned short)(u >> 16);
}
// packed pair via v_cvt_pk_bf16_f32 (RNE)
__device__ __forceinline__ unsigned pk2(float a, float b) {
    __hip_bfloat162 h = __float22bfloat162_rn(float2{a, b});
    unsigned r;
    __builtin_memcpy(&r, &h, sizeof(r));
    return r;
}

// ---- prep: Wp[h] = [112][104] bf16, exact LDS image ----
// rows 0..99 = W_h[o][f] (cols 100..103 = 0); row 100 = log2e*W_h^T att_src;
// row 101 = log2e*W_h^T att_dst; rows 102..111 = 0.
extern "C" __global__ void prep_w(const float* __restrict__ W,
                                  const float* __restrict__ att_src,
                                  const float* __restrict__ att_dst,
                                  unsigned short* __restrict__ Wp)
{
    const int h = blockIdx.x;      // 4
    const int f = threadIdx.x;     // 0..127
    const float* __restrict__ Wh = W + h * 10000;
    unsigned short* __restrict__ D = Wp + h * HSTRIDE;
    float ws = 0.0f, wd = 0.0f;
    if (f < 100) {
        for (int o = 0; o < 100; ++o) {
            float wv = Wh[o * 100 + f];
            ws = fmaf(att_src[h * 100 + o], wv, ws);
            wd = fmaf(att_dst[h * 100 + o], wv, wd);
        }
    }
    const float L2E = 1.44269504088896340736f;
    ws *= L2E; wd *= L2E;
    if (f < CST) {
        for (int o = 0; o < 100; ++o)
            D[o * CST + f] = (f < 100) ? f2bf(Wh[o * 100 + f]) : (unsigned short)0;
        D[100 * CST + f] = (f < 100) ? f2bf(ws) : (unsigned short)0;
        D[101 * CST + f] = (f < 100) ? f2bf(wd) : (unsigned short)0;
        for (int o = 102; o < 112; ++o) D[o * CST + f] = 0;
    }
}

// One block per t. 512 threads = 8 waves, one 16-row tile per wave (wave 7
// duplicates tile 6, writes suppressed). LDS 47488 B -> 3 blocks/CU.
// LDS: P  [112][104] bf16 @0     : X (until xf hoisted) -> W_h copy per head
//      HT [112][104] bf16 @23296 : H^T[o][j] per head
//      sas[112] @46592, sad[112] @47040 (f32); sas[100..111] = -2^127-ish kill
// 2 barriers/head (r10 structure). Logits come FREE from GEMM-1 tile 6
// (B-rows 100/101 = w~ vectors): lanes lr=4/5 store C-frag f32 to sas/sad.
// PVprep in exp2 domain (logits pre-scaled by log2e in prep).
extern "C" __global__ void __launch_bounds__(512, 6)
gat13(const float* __restrict__ A, const unsigned short* __restrict__ Wp,
      const float* __restrict__ bias, float* __restrict__ out)
{
    extern __shared__ char smem[];
    unsigned short* P  = (unsigned short*)smem;
    unsigned short* HT = (unsigned short*)(smem + 23296);
    float* sas  = (float*)(smem + 46592);
    float* sad  = (float*)(smem + 47040);
    float* sOut = (float*)smem;

    const int t    = blockIdx.x;
    const int tid  = threadIdx.x;      // 0..511
    const int w    = tid >> 6;         // 0..7
    const int l    = tid & 63;
    const int lr   = l & 15;
    const int lk   = l >> 4;
    const bool HASW = (w < 7);
    const int row  = HASW ? w : 6;     // wave 7 duplicates tile 6
    const int j0   = row * 16 + 4 * lk;        // 0..108
    const bool JW  = HASW && (j0 < 104);
    const float* __restrict__ At = A + (size_t)t * 10000u;
    const f32x4 z4 = {0, 0, 0, 0};

    // ---- zero P; init sas/sad (sas[100..111] large-negative) ----
    for (int i = tid; i < 1456; i += 512) ((f32x4*)smem)[i] = z4;
    if (tid < 224) {
        float v = (tid >= 100 && tid < 112) ? -1e30f : 0.0f;
        ((float*)(smem + 46592))[tid] = v;
    }
    __syncthreads();

    // ---- stage A_t^T -> P[n][f] bf16 (pk2 pairs along f) ----
#pragma unroll
    for (int k = 0; k < 3; ++k) {
        const int q = tid + k * 512;
        if (q < 1250) {
            const int fp = q / 25, n0 = (q - fp * 25) * 4, f = fp * 2;
            float4 va = *(const float4*)(At + f * 100 + n0);
            float4 vb = *(const float4*)(At + (f + 1) * 100 + n0);
            *(unsigned*)(P + (n0 + 0) * CST + f) = pk2(va.x, vb.x);
            *(unsigned*)(P + (n0 + 1) * CST + f) = pk2(va.y, vb.y);
            *(unsigned*)(P + (n0 + 2) * CST + f) = pk2(va.z, vb.z);
            *(unsigned*)(P + (n0 + 3) * CST + f) = pk2(va.w, vb.w);
        }
    }
    __syncthreads();

    // ---- hoist X fragments ----
    const bf16x8 zf = {0, 0, 0, 0, 0, 0, 0, 0};
    bf16x8 xf[4];
#pragma unroll
    for (int ks = 0; ks < 4; ++ks) {
        const bool kill = (ks == 3) && (lk != 0);
        const int koff = kill ? 96 : ks * 32 + lk * 8;
        bf16x8 v = *(const bf16x8*)(P + (row * 16 + lr) * CST + koff);
        xf[ks] = kill ? zf : v;
    }
    __syncthreads();   // hoist done -> P writable

    f32x4 acc[7];
#pragma unroll
    for (int c = 0; c < 7; ++c) acc[c] = z4;

    for (int h = 0; h < 4; ++h) {
        // ---- Wfill: pure 16B copy of prepped head image into P ----
        {
            const u32x4* __restrict__ Wg = (const u32x4*)(Wp + h * HSTRIDE);
#pragma unroll
            for (int k = 0; k < 3; ++k) {
                const int q = tid + k * 512;
                if (q < 1456) ((u32x4*)P)[q] = Wg[q];
            }
        }
        __syncthreads();   // (b) W ready; also fences prev PV's HT reads

        // ---- GEMM-1, two N-halves; logits free from tile 6 ----
#pragma unroll
        for (int half = 0; half < 2; ++half) {
            const int ntn = half ? 3 : 4;
            f32x4 c[4];
#pragma unroll
            for (int cc = 0; cc < 4; ++cc) c[cc] = z4;
#pragma unroll
            for (int ks = 0; ks < 4; ++ks) {
                const int koff = ks * 32 + lk * 8;   // A-side zero kills k-pad
                bf16x8 b[4];
#pragma unroll
                for (int bb = 0; bb < 4; ++bb)
                    if (bb < ntn)
                        b[bb] = *(const bf16x8*)(P + ((half * 4 + bb) * 16 + lr) * CST + koff);
#pragma unroll
                for (int bb = 0; bb < 4; ++bb)
                    if (bb < ntn)
                        c[bb] = __builtin_amdgcn_mfma_f32_16x16x32_bf16(xf[ks], b[bb], c[bb], 0, 0, 0);
            }
#pragma unroll
            for (int bb = 0; bb < 4; ++bb)
                if (bb < ntn) {
                    const int o = (half * 4 + bb) * 16 + lr;
                    if (JW) {
                        uint2 pp;
                        pp.x = pk2(c[bb].x, c[bb].y);
                        pp.y = pk2(c[bb].z, c[bb].w);
                        *(uint2*)(HT + o * CST + j0) = pp;
                    }
                }
            if (half == 1) {   // tile 6 C-cols 100/101 = a_s', a_d' (log2 domain)
                if (lr == 4 && HASW && j0 < 100) *(f32x4*)(sas + j0) = c[2];
                if (lr == 5 && JW)               *(f32x4*)(sad + j0) = c[2];
            }
        }
        __syncthreads();   // (c) HT + sas/sad ready

        // ---- PVprep: exp2-domain E + row-sum, normalize, pack bf16 ----
        const float adi = sad[row * 16 + lr];
        float ev[32];
        float sE = 0.0f;
#pragma unroll
        for (int ks = 0; ks < 4; ++ks) {
            const bool dead = (ks == 3) && (lk != 0);
            const int jb = dead ? 64 : ks * 32 + lk * 8;
            const f32x4 s0 = *(const f32x4*)(sas + jb);
            const f32x4 s1 = *(const f32x4*)(sas + jb + 4);
            ev[ks * 8 + 0] = dead ? 0.0f : exp2f(lrelu(adi + s0.x));
            ev[ks * 8 + 1] = dead ? 0.0f : exp2f(lrelu(adi + s0.y));
            ev[ks * 8 + 2] = dead ? 0.0f : exp2f(lrelu(adi + s0.z));
            ev[ks * 8 + 3] = dead ? 0.0f : exp2f(lrelu(adi + s0.w));
            ev[ks * 8 + 4] = dead ? 0.0f : exp2f(lrelu(adi + s1.x));
            ev[ks * 8 + 5] = dead ? 0.0f : exp2f(lrelu(adi + s1.y));
            ev[ks * 8 + 6] = dead ? 0.0f : exp2f(lrelu(adi + s1.z));
            ev[ks * 8 + 7] = dead ? 0.0f : exp2f(lrelu(adi + s1.w));
#pragma unroll
            for (int jj = 0; jj < 8; ++jj) sE += ev[ks * 8 + jj];
        }
        sE += __shfl_xor(sE, 16);
        sE += __shfl_xor(sE, 32);
        const float invE = sE > 0.0f ? __builtin_amdgcn_rcpf(sE) : 0.0f;
        bf16x8 af[4];
#pragma unroll
        for (int ks = 0; ks < 4; ++ks) {
            u32x4 uv;
            uv.x = pk2(ev[ks * 8 + 0] * invE, ev[ks * 8 + 1] * invE);
            uv.y = pk2(ev[ks * 8 + 2] * invE, ev[ks * 8 + 3] * invE);
            uv.z = pk2(ev[ks * 8 + 4] * invE, ev[ks * 8 + 5] * invE);
            uv.w = pk2(ev[ks * 8 + 6] * invE, ev[ks * 8 + 7] * invE);
            af[ks] = __builtin_bit_cast(bf16x8, uv);
        }

        // ---- PV: acc += alpha * H (direct C accumulation) ----
#pragma unroll
        for (int half = 0; half < 2; ++half) {
            const int ntn = half ? 3 : 4;
#pragma unroll
            for (int ks = 0; ks < 4; ++ks) {
                const int koff = ks * 32 + lk * 8;
                bf16x8 b[4];
#pragma unroll
                for (int bb = 0; bb < 4; ++bb)
                    if (bb < ntn)
                        b[bb] = *(const bf16x8*)(HT + ((half * 4 + bb) * 16 + lr) * CST + koff);
#pragma unroll
                for (int bb = 0; bb < 4; ++bb)
                    if (bb < ntn)
                        acc[half * 4 + bb] = __builtin_amdgcn_mfma_f32_16x16x32_bf16(
                            af[ks], b[bb], acc[half * 4 + bb], 0, 0, 0);
            }
        }
    }
    __syncthreads();   // all PV done; P+HT dead -> sOut overlay

    // ---- epilogue: sOut[o][i] = lrelu(acc*0.25 + bias[o]) + (i==o) ----
    if (JW) {
        const int i0 = j0;
#pragma unroll
        for (int tn = 0; tn < 7; ++tn) {
            const int o = tn * 16 + lr;
            const float b = (o < 100) ? bias[o] : 0.0f;
            f32x4 v;
            v.x = lrelu(acc[tn].x * 0.25f + b) + ((i0 + 0) == o ? 1.0f : 0.0f);
            v.y = lrelu(acc[tn].y * 0.25f + b) + ((i0 + 1) == o ? 1.0f : 0.0f);
            v.z = lrelu(acc[tn].z * 0.25f + b) + ((i0 + 2) == o ? 1.0f : 0.0f);
            v.w = lrelu(acc[tn].w * 0.25f + b) + ((i0 + 3) == o ? 1.0f : 0.0f);
            *(f32x4*)(sOut + o * 104 + i0) = v;
        }
    }
    __syncthreads();

    // ---- coalesced store out[t][o][i] ----
    float* __restrict__ outT = out + (size_t)t * 10000u;
    for (int q = tid; q < 2500; q += 512) {
        int o = q / 25, i0 = (q - o * 25) * 4;
        *(float4*)(outT + o * 100 + i0) = *(const float4*)(sOut + o * 104 + i0);
    }
}

extern "C" void kernel_launch(void* const* d_in, const int* in_sizes, int n_in,
                              void* d_out, int out_size, void* d_ws, size_t ws_size,
                              hipStream_t stream) {
    const float* A      = (const float*)d_in[0];
    const float* W      = (const float*)d_in[1];
    const float* attsrc = (const float*)d_in[2];
    const float* attdst = (const float*)d_in[3];
    const float* bias   = (const float*)d_in[4];
    float* outp = (float*)d_out;
    unsigned short* Wp = (unsigned short*)d_ws;   // 4*11648*2 = 93184 B

    const int T = in_sizes[0] / 10000;   // 1024

    prep_w<<<4, 128, 0, stream>>>(W, attsrc, attdst, Wp);

    const int smem_bytes = 47488;
    gat13<<<T, 512, smem_bytes, stream>>>(A, Wp, bias, outp);
}